// Round 8
// baseline (669.400 us; speedup 1.0000x reference)
//
#include <hip/hip_runtime.h>
#include <math.h>

#define BB 8
#define NN 10000
#define EE 320000

// ---- ws layout (float offsets) ----
#define OFF_MM   0         // 16 floats (uint min/max slots)
#define OFF_WIND 16        // 2*B*N
#define OFF_PRE1 160016    // 32*B*N
#define OFF_PRE2 2720016   // 32*B*N
#define OFF_CNT  5280016   // 2*N uint      (CSR path only)
#define OFF_OFF  5300016   // 2*(N+1) uint  (CSR path only)
#define OFF_CUR  5320018   // 2*N uint      (CSR path only)
#define OFF_LST  5340018   // 2*E uint      (CSR path only)
#define OFF_G    5980032   // nb*E*16 floats, 16B aligned (CSR path only)

__device__ __forceinline__ float sigmf(float x) {
    return __fdividef(1.0f, 1.0f + __expf(-x));
}

// ---------------- init min/max slots ----------------
__global__ void init_mm(unsigned* mm) {
    int t = threadIdx.x;
    if (t < 2) mm[t] = 0x7F7FFFFFu;       // +FLT_MAX bits (min slots)
    else if (t < 4) mm[t] = 0u;           // 0 (max slots; values >= 0)
}

// ---------------- minmax only (fallback path; touches nothing past pre2) ----
__global__ __launch_bounds__(256) void minmax_kernel(const float* __restrict__ ea,
                                                     unsigned* __restrict__ mm) {
    int t = blockIdx.x * 256 + threadIdx.x;
    float2 v = ((const float2*)ea)[t];
    float mn0 = v.x, mx0 = v.x, mn1 = v.y, mx1 = v.y;
    #pragma unroll
    for (int off = 32; off >= 1; off >>= 1) {
        mn0 = fminf(mn0, __shfl_xor(mn0, off));
        mx0 = fmaxf(mx0, __shfl_xor(mx0, off));
        mn1 = fminf(mn1, __shfl_xor(mn1, off));
        mx1 = fmaxf(mx1, __shfl_xor(mx1, off));
    }
    if ((threadIdx.x & 63) == 0) {
        atomicMin(&mm[0], __float_as_uint(mn0));
        atomicMin(&mm[1], __float_as_uint(mn1));
        atomicMax(&mm[2], __float_as_uint(mx0));
        atomicMax(&mm[3], __float_as_uint(mx1));
    }
}

// ---------------- prep: degree count + edge_attr min/max (CSR path) --------
__global__ __launch_bounds__(256) void prep_kernel(const int* __restrict__ ei,
                                                   const float* __restrict__ ea,
                                                   unsigned* __restrict__ cnt,
                                                   unsigned* __restrict__ mm) {
    int t = blockIdx.x * 256 + threadIdx.x;
    int v = ei[t];
    atomicAdd(&cnt[(t < EE ? 0 : NN) + v], 1u);
    if (t < EE) {
        float2 vv = ((const float2*)ea)[t];
        float mn0 = vv.x, mx0 = vv.x, mn1 = vv.y, mx1 = vv.y;
        #pragma unroll
        for (int off = 32; off >= 1; off >>= 1) {
            mn0 = fminf(mn0, __shfl_xor(mn0, off));
            mx0 = fmaxf(mx0, __shfl_xor(mx0, off));
            mn1 = fminf(mn1, __shfl_xor(mn1, off));
            mx1 = fmaxf(mx1, __shfl_xor(mx1, off));
        }
        if ((threadIdx.x & 63) == 0) {
            atomicMin(&mm[0], __float_as_uint(mn0));
            atomicMin(&mm[1], __float_as_uint(mn1));
            atomicMax(&mm[2], __float_as_uint(mx0));
            atomicMax(&mm[3], __float_as_uint(mx1));
        }
    }
}

// ---------------- per-node precompute ----------------
__global__ __launch_bounds__(256) void node_pre(const float* __restrict__ x,
                                                const float* __restrict__ W1,
                                                const float* __restrict__ wmin,
                                                const float* __restrict__ wmax,
                                                float* __restrict__ pre1,
                                                float* __restrict__ pre2,
                                                float* __restrict__ wind) {
    int id = blockIdx.x * 256 + threadIdx.x;
    if (id >= BB * NN) return;
    float xv[16];
    const float4* xp = (const float4*)(x + (size_t)id * 16);
    #pragma unroll
    for (int q = 0; q < 4; q++) {
        float4 v = xp[q];
        xv[4 * q + 0] = v.x; xv[4 * q + 1] = v.y;
        xv[4 * q + 2] = v.z; xv[4 * q + 3] = v.w;
    }
    float s1[32], s2[32];
    #pragma unroll
    for (int j = 0; j < 32; j++) { s1[j] = 0.f; s2[j] = 0.f; }
    #pragma unroll
    for (int r = 0; r < 16; r++) {
        float xr = xv[r];
        #pragma unroll
        for (int j = 0; j < 32; j++) {
            s1[j] = fmaf(xr, W1[r * 32 + j], s1[j]);
            s2[j] = fmaf(xr, W1[(16 + r) * 32 + j], s2[j]);
        }
    }
    float4* o1 = (float4*)(pre1 + (size_t)id * 32);
    float4* o2 = (float4*)(pre2 + (size_t)id * 32);
    #pragma unroll
    for (int q = 0; q < 8; q++) {
        o1[q] = make_float4(s1[4*q], s1[4*q+1], s1[4*q+2], s1[4*q+3]);
        o2[q] = make_float4(s2[4*q], s2[4*q+1], s2[4*q+2], s2[4*q+3]);
    }
    float sp = xv[14] * (wmax[0] - wmin[0]) + wmin[0];
    float dr = xv[15] * (wmax[1] - wmin[1]) + wmin[1];
    ((float2*)wind)[id] = make_float2(sp, dr);
}

// ---------------- CSR scan: exclusive prefix over both count arrays --------
__global__ __launch_bounds__(1024) void scan_kernel(const unsigned* __restrict__ cnt,
                                                    unsigned* __restrict__ offp,
                                                    unsigned* __restrict__ cur) {
    __shared__ unsigned ts[1024];
    int t = threadIdx.x;
    const int CH = 10;                       // 1024*10 >= 10000
    for (int a = 0; a < 2; a++) {
        const unsigned* c = cnt + a * NN;
        unsigned* off = offp + a * (NN + 1);
        unsigned* cu  = cur + a * NN;
        unsigned s = 0;
        int i0 = t * CH;
        #pragma unroll
        for (int k = 0; k < CH; k++) { int i = i0 + k; if (i < NN) s += c[i]; }
        ts[t] = s;
        __syncthreads();
        for (int d = 1; d < 1024; d <<= 1) {
            unsigned v = (t >= d) ? ts[t - d] : 0u;
            __syncthreads();
            ts[t] += v;
            __syncthreads();
        }
        unsigned run = ts[t] - s;            // exclusive base for this chunk
        #pragma unroll
        for (int k = 0; k < CH; k++) {
            int i = i0 + k;
            if (i < NN) { unsigned cv = c[i]; off[i] = run; cu[i] = run; run += cv; }
        }
        if (t == 1023) off[NN] = ts[1023];
        __syncthreads();
    }
}

// ---------------- CSR fill ----------------
__global__ __launch_bounds__(256) void fill_kernel(const int* __restrict__ ei,
                                                   unsigned* __restrict__ cur,
                                                   unsigned* __restrict__ lst) {
    int t = blockIdx.x * 256 + threadIdx.x;  // [0, 2E)
    int v = ei[t];
    bool isrc = t < EE;
    unsigned p = atomicAdd(&cur[(isrc ? 0 : NN) + v], 1u);
    lst[(isrc ? 0 : EE) + p] = isrc ? t : (t - EE);
}

// ---------------- phase B: edge MLP -> g[e][b][16] (no atomics) ----------
__global__ __launch_bounds__(256) void edge_mlp(const int* __restrict__ ei,
                                                const float* __restrict__ ea,
                                                const float* __restrict__ pre1,
                                                const float* __restrict__ pre2,
                                                const float* __restrict__ wind,
                                                const float* __restrict__ mm,
                                                const float* __restrict__ W1,
                                                const float* __restrict__ b1,
                                                const float* __restrict__ W2,
                                                const float* __restrict__ b2,
                                                const float* __restrict__ Wn,
                                                float* __restrict__ gbuf,
                                                int b0, int nb) {
    __shared__ float gs[256 * 17];           // padded stride 17

    const int tid = threadIdx.x;
    const int e = blockIdx.x * 256 + tid;
    const int brel = blockIdx.y;
    const int b = b0 + brel;

    const int src = ei[e];
    const int tgt = ei[EE + e];
    const float2 eav = ((const float2*)ea)[e];
    const float2 wv = ((const float2*)wind)[(size_t)b * NN + src];

    float theta = fabsf(eav.y - wv.y);
    float ew = fmaxf(__fdividef(wv.x * cosf(theta), eav.x), 0.f);
    float ean0 = __fdividef(eav.x - mm[0], mm[2] - mm[0]);
    float ean1 = __fdividef(eav.y - mm[1], mm[3] - mm[1]);

    float h[32];
    const float4* p1 = (const float4*)(pre1 + ((size_t)b * NN + src) * 32);
    const float4* p2 = (const float4*)(pre2 + ((size_t)b * NN + tgt) * 32);
    #pragma unroll
    for (int q = 0; q < 8; q++) {
        float4 a = p1[q];
        float4 c = p2[q];
        h[4*q+0] = a.x + c.x; h[4*q+1] = a.y + c.y;
        h[4*q+2] = a.z + c.z; h[4*q+3] = a.w + c.w;
    }
    #pragma unroll
    for (int j = 0; j < 32; j++) {
        float v = h[j] + ean0 * W1[32 * 32 + j] + ean1 * W1[33 * 32 + j]
                        + ew * W1[34 * 32 + j] + b1[j];
        h[j] = sigmf(v);
    }

    float ef[22];
    #pragma unroll
    for (int k = 0; k < 22; k++) ef[k] = b2[k];
    #pragma unroll
    for (int j = 0; j < 32; j++) {
        float hv = h[j];
        #pragma unroll
        for (int k = 0; k < 22; k++) ef[k] = fmaf(hv, W2[j * 22 + k], ef[k]);
    }
    #pragma unroll
    for (int k = 0; k < 22; k++) ef[k] = sigmf(ef[k]);

    float gg[16];
    #pragma unroll
    for (int i = 0; i < 16; i++) gg[i] = 0.f;
    #pragma unroll
    for (int k = 0; k < 22; k++) {
        float ev = ef[k];
        #pragma unroll
        for (int i = 0; i < 16; i++) gg[i] = fmaf(ev, Wn[k * 16 + i], gg[i]);
    }

    // transpose through LDS, coalesced 64B-segment stores to gbuf
    #pragma unroll
    for (int i = 0; i < 16; i++) gs[tid * 17 + i] = gg[i];
    __syncthreads();

    const int c = tid & 15;
    const int base = tid >> 4;
    const size_t ebase = (size_t)blockIdx.x * 256;
    #pragma unroll
    for (int p = 0; p < 16; p++) {
        int s = base + p * 16;
        gbuf[((ebase + s) * (size_t)nb + brel) * 16 + c] = gs[s * 17 + c];
    }
}

// ---------------- phase C: per-node gather + bn + sigmoid ----------------
__global__ __launch_bounds__(256) void gather_kernel(const unsigned* __restrict__ offp,
                                                     const unsigned* __restrict__ lst,
                                                     const float* __restrict__ gbuf,
                                                     const float* __restrict__ bn,
                                                     float* __restrict__ out,
                                                     int b0, int nb, int npb, int lgper) {
    int tid = threadIdx.x;
    int n = blockIdx.x * npb + (tid >> lgper);
    int rem = tid & ((1 << lgper) - 1);
    int bi = rem >> 4;
    int c = rem & 15;

    unsigned s0 = offp[n], s1 = offp[n + 1];
    unsigned t0 = offp[NN + 1 + n], t1 = offp[NN + 1 + n + 1];

    float acc = 0.f;
    for (unsigned k = t0; k < t1; k++) {                 // in-edges: +
        int e = (int)lst[EE + k];
        acc += gbuf[((size_t)e * nb + bi) * 16 + c];
    }
    for (unsigned k = s0; k < s1; k++) {                 // out-edges: -
        int e = (int)lst[k];
        acc -= gbuf[((size_t)e * nb + bi) * 16 + c];
    }
    out[((size_t)(b0 + bi) * NN + n) * 16 + c] = sigmf(acc + bn[c]);
}

// ================= fallback (atomic) path, proven-correct r5 =================
__global__ __launch_bounds__(256) void edge_kernel(const int* __restrict__ ei,
                                                   const float* __restrict__ ea,
                                                   const float* __restrict__ pre1,
                                                   const float* __restrict__ pre2,
                                                   const float* __restrict__ wind,
                                                   const float* __restrict__ mm,
                                                   const float* __restrict__ W1,
                                                   const float* __restrict__ b1,
                                                   const float* __restrict__ W2,
                                                   const float* __restrict__ b2,
                                                   const float* __restrict__ Wn,
                                                   float* __restrict__ out) {
    __shared__ float gs[256 * 17];
    __shared__ int nd[512];
    const int tid = threadIdx.x;
    const int e = blockIdx.x * 256 + tid;
    const int b = blockIdx.y;
    const int src = ei[e];
    const int tgt = ei[EE + e];
    const float2 eav = ((const float2*)ea)[e];
    const float2 wv = ((const float2*)wind)[(size_t)b * NN + src];
    float theta = fabsf(eav.y - wv.y);
    float ew = fmaxf(__fdividef(wv.x * cosf(theta), eav.x), 0.f);
    float ean0 = __fdividef(eav.x - mm[0], mm[2] - mm[0]);
    float ean1 = __fdividef(eav.y - mm[1], mm[3] - mm[1]);
    float h[32];
    const float4* p1 = (const float4*)(pre1 + ((size_t)b * NN + src) * 32);
    const float4* p2 = (const float4*)(pre2 + ((size_t)b * NN + tgt) * 32);
    #pragma unroll
    for (int q = 0; q < 8; q++) {
        float4 a = p1[q]; float4 c = p2[q];
        h[4*q+0] = a.x + c.x; h[4*q+1] = a.y + c.y;
        h[4*q+2] = a.z + c.z; h[4*q+3] = a.w + c.w;
    }
    #pragma unroll
    for (int j = 0; j < 32; j++) {
        float v = h[j] + ean0 * W1[32*32+j] + ean1 * W1[33*32+j] + ew * W1[34*32+j] + b1[j];
        h[j] = sigmf(v);
    }
    float ef[22];
    #pragma unroll
    for (int k = 0; k < 22; k++) ef[k] = b2[k];
    #pragma unroll
    for (int j = 0; j < 32; j++) {
        float hv = h[j];
        #pragma unroll
        for (int k = 0; k < 22; k++) ef[k] = fmaf(hv, W2[j*22+k], ef[k]);
    }
    #pragma unroll
    for (int k = 0; k < 22; k++) ef[k] = sigmf(ef[k]);
    float g[16];
    #pragma unroll
    for (int i = 0; i < 16; i++) g[i] = 0.f;
    #pragma unroll
    for (int k = 0; k < 22; k++) {
        float ev = ef[k];
        #pragma unroll
        for (int i = 0; i < 16; i++) g[i] = fmaf(ev, Wn[k*16+i], g[i]);
    }
    nd[tid] = tgt; nd[256 + tid] = src;
    #pragma unroll
    for (int i = 0; i < 16; i++) gs[tid * 17 + i] = g[i];
    __syncthreads();
    const int c = tid & 15;
    const int base = tid >> 4;
    float* aggb = out + (size_t)b * NN * 16;
    for (int p = 0; p < 16; p++) {
        int s = base + p * 16;
        float val = gs[s * 17 + c];
        atomicAdd(&aggb[(size_t)nd[s] * 16 + c], val);
        atomicAdd(&aggb[(size_t)nd[256 + s] * 16 + c], -val);
    }
}

__global__ __launch_bounds__(256) void epilogue(float* __restrict__ out,
                                                const float* __restrict__ bn) {
    int id = blockIdx.x * 256 + threadIdx.x;
    if (id >= BB * NN * 4) return;
    float4 v = ((float4*)out)[id];
    int q = (id & 3) * 4;
    v.x = sigmf(v.x + bn[q + 0]);
    v.y = sigmf(v.y + bn[q + 1]);
    v.z = sigmf(v.z + bn[q + 2]);
    v.w = sigmf(v.w + bn[q + 3]);
    ((float4*)out)[id] = v;
}

extern "C" void kernel_launch(void* const* d_in, const int* in_sizes, int n_in,
                              void* d_out, int out_size, void* d_ws, size_t ws_size,
                              hipStream_t stream) {
    const float* x    = (const float*)d_in[0];
    const int*   ei   = (const int*)d_in[1];
    const float* ea   = (const float*)d_in[2];
    const float* wmin = (const float*)d_in[3];
    const float* wmax = (const float*)d_in[4];
    const float* W1   = (const float*)d_in[5];
    const float* b1   = (const float*)d_in[6];
    const float* W2   = (const float*)d_in[7];
    const float* b2   = (const float*)d_in[8];
    const float* Wn   = (const float*)d_in[9];
    const float* bn   = (const float*)d_in[10];
    float* out = (float*)d_out;

    float* ws      = (float*)d_ws;
    unsigned* mm   = (unsigned*)(ws + OFF_MM);
    const float* mmf = (const float*)(ws + OFF_MM);
    float* wind    = ws + OFF_WIND;
    float* pre1    = ws + OFF_PRE1;
    float* pre2    = ws + OFF_PRE2;
    unsigned* cnt  = (unsigned*)(ws + OFF_CNT);
    unsigned* offp = (unsigned*)(ws + OFF_OFF);
    unsigned* cur  = (unsigned*)(ws + OFF_CUR);
    unsigned* lst  = (unsigned*)(ws + OFF_LST);
    float* gbuf    = ws + OFF_G;

    // pick batch-chunk size nb so g fits in ws; fall back to atomic path if none fits
    int nb = 8;
    while (nb > 1 && ((size_t)OFF_G + (size_t)nb * EE * 16) * 4ull > ws_size) nb >>= 1;
    bool csr_ok = ((size_t)OFF_G + (size_t)nb * EE * 16) * 4ull <= ws_size;

    init_mm<<<1, 64, 0, stream>>>(mm);
    node_pre<<<(BB * NN + 255) / 256, 256, 0, stream>>>(x, W1, wmin, wmax, pre1, pre2, wind);

    if (csr_ok) {
        hipMemsetAsync(cnt, 0, 2 * NN * sizeof(unsigned), stream);
        prep_kernel<<<2 * EE / 256, 256, 0, stream>>>(ei, ea, cnt, mm);
        scan_kernel<<<1, 1024, 0, stream>>>(cnt, offp, cur);
        fill_kernel<<<2 * EE / 256, 256, 0, stream>>>(ei, cur, lst);

        int lgnb = (nb == 8) ? 3 : (nb == 4) ? 2 : (nb == 2) ? 1 : 0;
        int per = 16 * nb;
        int npb = 256 / per;
        int lgper = 4 + lgnb;
        for (int bc = 0; bc < BB; bc += nb) {
            edge_mlp<<<dim3(EE / 256, nb), 256, 0, stream>>>(ei, ea, pre1, pre2, wind,
                                                             mmf, W1, b1, W2, b2, Wn,
                                                             gbuf, bc, nb);
            gather_kernel<<<NN / npb, 256, 0, stream>>>(offp, lst, gbuf, bn, out,
                                                        bc, nb, npb, lgper);
        }
    } else {
        // atomic fallback — byte-identical ws footprint to the round-5 validated kernel
        minmax_kernel<<<EE / 256, 256, 0, stream>>>(ea, mm);
        hipMemsetAsync(d_out, 0, (size_t)out_size * sizeof(float), stream);
        edge_kernel<<<dim3(EE / 256, BB), 256, 0, stream>>>(ei, ea, pre1, pre2, wind,
                                                            mmf, W1, b1, W2, b2, Wn, out);
        epilogue<<<(BB * NN * 4 + 255) / 256, 256, 0, stream>>>(out, bn);
    }
}

// Round 9
// 419.999 us; speedup vs baseline: 1.5938x; 1.5938x over previous
//
#include <hip/hip_runtime.h>
#include <math.h>

#define BB 8
#define NN 10000
#define EE 320000
#define NCHUNK 128
#define CHSZ (EE / NCHUNK)   // 2500

// ---- ws layout (float offsets) ----
#define OFF_MM   0           // 16 floats (mm as float on CSR path; uint slots on fallback)
#define OFF_WIND 16          // 2*B*N
#define OFF_PRE1 160016      // 32*B*N
#define OFF_PRE2 2720016     // 32*B*N
#define OFF_OFFP 5280016     // 2*(N+1) uint
#define OFF_TOT  5300018     // 2*N uint
#define OFF_MMP  5320018     // NCHUNK*4 floats
#define OFF_CNTC 5320530     // 2*NCHUNK*N uint (becomes per-chunk bases in place)
#define OFF_LST  7880530     // 2*E uint
#define OFF_G    8520544     // nb*E*16 floats, 64B aligned

__device__ __forceinline__ float sigmf(float x) {
    return __fdividef(1.0f, 1.0f + __expf(-x));
}

// ================= CSR build: zero global atomics =================

// count: one block per (chunk, array). LDS histogram + per-chunk ea min/max partials.
__global__ __launch_bounds__(256) void count_kernel(const int* __restrict__ ei,
                                                    const float* __restrict__ ea,
                                                    unsigned* __restrict__ cntc,
                                                    float* __restrict__ mmpart) {
    __shared__ unsigned hist[NN];           // 40 KB
    __shared__ float mred[4][4];
    const int c = blockIdx.x, a = blockIdx.y, tid = threadIdx.x;
    for (int i = tid; i < NN; i += 256) hist[i] = 0u;
    __syncthreads();
    const int e0 = c * CHSZ;
    float n0 = 3.4e38f, n1 = 3.4e38f, x0 = 0.f, x1 = 0.f;
    for (int k = tid; k < CHSZ; k += 256) {
        int v = ei[(size_t)a * EE + e0 + k];
        atomicAdd(&hist[v], 1u);            // LDS atomic
        if (a == 0) {
            float2 av = ((const float2*)ea)[e0 + k];
            n0 = fminf(n0, av.x); x0 = fmaxf(x0, av.x);
            n1 = fminf(n1, av.y); x1 = fmaxf(x1, av.y);
        }
    }
    __syncthreads();
    unsigned* dst = cntc + ((size_t)a * NCHUNK + c) * NN;
    for (int i = tid; i < NN; i += 256) dst[i] = hist[i];
    if (a == 0) {                            // block-uniform branch (a = blockIdx.y)
        #pragma unroll
        for (int off = 32; off >= 1; off >>= 1) {
            n0 = fminf(n0, __shfl_xor(n0, off)); n1 = fminf(n1, __shfl_xor(n1, off));
            x0 = fmaxf(x0, __shfl_xor(x0, off)); x1 = fmaxf(x1, __shfl_xor(x1, off));
        }
        int w = tid >> 6;
        if ((tid & 63) == 0) { mred[w][0] = n0; mred[w][1] = n1; mred[w][2] = x0; mred[w][3] = x1; }
        __syncthreads();
        if (tid == 0) {
            mmpart[c * 4 + 0] = fminf(fminf(mred[0][0], mred[1][0]), fminf(mred[2][0], mred[3][0]));
            mmpart[c * 4 + 1] = fminf(fminf(mred[0][1], mred[1][1]), fminf(mred[2][1], mred[3][1]));
            mmpart[c * 4 + 2] = fmaxf(fmaxf(mred[0][2], mred[1][2]), fmaxf(mred[2][2], mred[3][2]));
            mmpart[c * 4 + 3] = fmaxf(fmaxf(mred[0][3], mred[1][3]), fmaxf(mred[2][3], mred[3][3]));
        }
    }
}

// tot[a][v] = sum over chunks (coalesced in v)
__global__ __launch_bounds__(256) void tot_kernel(const unsigned* __restrict__ cntc,
                                                  unsigned* __restrict__ tot) {
    int v = blockIdx.x * 256 + threadIdx.x;
    int a = blockIdx.y;
    if (v >= NN) return;
    const unsigned* base = cntc + (size_t)a * NCHUNK * NN;
    unsigned s = 0;
    for (int c = 0; c < NCHUNK; c++) s += base[(size_t)c * NN + v];
    tot[a * NN + v] = s;
}

// single block: reduce mm partials + exclusive scan tot -> offp
__global__ __launch_bounds__(1024) void scan_kernel(const unsigned* __restrict__ tot,
                                                    const float* __restrict__ mmpart,
                                                    unsigned* __restrict__ offp,
                                                    float* __restrict__ mmo) {
    __shared__ unsigned ts[1024];
    int t = threadIdx.x;
    if (t < 64) {
        float n0 = fminf(mmpart[4 * t + 0], mmpart[4 * (t + 64) + 0]);
        float n1 = fminf(mmpart[4 * t + 1], mmpart[4 * (t + 64) + 1]);
        float x0 = fmaxf(mmpart[4 * t + 2], mmpart[4 * (t + 64) + 2]);
        float x1 = fmaxf(mmpart[4 * t + 3], mmpart[4 * (t + 64) + 3]);
        #pragma unroll
        for (int off = 32; off >= 1; off >>= 1) {
            n0 = fminf(n0, __shfl_xor(n0, off)); n1 = fminf(n1, __shfl_xor(n1, off));
            x0 = fmaxf(x0, __shfl_xor(x0, off)); x1 = fmaxf(x1, __shfl_xor(x1, off));
        }
        if (t == 0) { mmo[0] = n0; mmo[1] = n1; mmo[2] = x0; mmo[3] = x1; }
    }
    const int CH = 10;                       // 1024*10 >= 10000
    for (int a = 0; a < 2; a++) {
        const unsigned* c = tot + a * NN;
        unsigned* off = offp + a * (NN + 1);
        unsigned s = 0;
        int i0 = t * CH;
        #pragma unroll
        for (int k = 0; k < CH; k++) { int i = i0 + k; if (i < NN) s += c[i]; }
        ts[t] = s;
        __syncthreads();
        for (int d = 1; d < 1024; d <<= 1) {
            unsigned v = (t >= d) ? ts[t - d] : 0u;
            __syncthreads();
            ts[t] += v;
            __syncthreads();
        }
        unsigned run = ts[t] - s;
        #pragma unroll
        for (int k = 0; k < CH; k++) {
            int i = i0 + k;
            if (i < NN) { unsigned cv = c[i]; off[i] = run; run += cv; }
        }
        if (t == 1023) off[NN] = ts[1023];
        __syncthreads();
    }
}

// base: in place, cntc[a][c][v] <- offp[a][v] + prefix_{c'<c} cntc[a][c'][v]
__global__ __launch_bounds__(256) void base_kernel(unsigned* __restrict__ cntc,
                                                   const unsigned* __restrict__ offp) {
    int v = blockIdx.x * 256 + threadIdx.x;
    int a = blockIdx.y;
    if (v >= NN) return;
    unsigned run = offp[a * (NN + 1) + v];
    unsigned* base = cntc + (size_t)a * NCHUNK * NN;
    for (int c = 0; c < NCHUNK; c++) {
        unsigned cv = base[(size_t)c * NN + v];
        base[(size_t)c * NN + v] = run;
        run += cv;
    }
}

// fill: LDS cursors only; global stores are plain (unique slots by construction)
__global__ __launch_bounds__(256) void fill_kernel(const int* __restrict__ ei,
                                                   const unsigned* __restrict__ cntc,
                                                   unsigned* __restrict__ lst) {
    __shared__ unsigned cur[NN];             // 40 KB
    const int c = blockIdx.x, a = blockIdx.y, tid = threadIdx.x;
    const unsigned* bs = cntc + ((size_t)a * NCHUNK + c) * NN;
    for (int i = tid; i < NN; i += 256) cur[i] = bs[i];
    __syncthreads();
    const int e0 = c * CHSZ;
    for (int k = tid; k < CHSZ; k += 256) {
        int e = e0 + k;
        int v = ei[(size_t)a * EE + e];
        unsigned p = atomicAdd(&cur[v], 1u); // LDS atomic
        lst[(size_t)a * EE + p] = (unsigned)e;
    }
}

// ================= per-node precompute =================
__global__ __launch_bounds__(256) void node_pre(const float* __restrict__ x,
                                                const float* __restrict__ W1,
                                                const float* __restrict__ wmin,
                                                const float* __restrict__ wmax,
                                                float* __restrict__ pre1,
                                                float* __restrict__ pre2,
                                                float* __restrict__ wind) {
    int id = blockIdx.x * 256 + threadIdx.x;
    if (id >= BB * NN) return;
    float xv[16];
    const float4* xp = (const float4*)(x + (size_t)id * 16);
    #pragma unroll
    for (int q = 0; q < 4; q++) {
        float4 v = xp[q];
        xv[4 * q + 0] = v.x; xv[4 * q + 1] = v.y;
        xv[4 * q + 2] = v.z; xv[4 * q + 3] = v.w;
    }
    float s1[32], s2[32];
    #pragma unroll
    for (int j = 0; j < 32; j++) { s1[j] = 0.f; s2[j] = 0.f; }
    #pragma unroll
    for (int r = 0; r < 16; r++) {
        float xr = xv[r];
        #pragma unroll
        for (int j = 0; j < 32; j++) {
            s1[j] = fmaf(xr, W1[r * 32 + j], s1[j]);
            s2[j] = fmaf(xr, W1[(16 + r) * 32 + j], s2[j]);
        }
    }
    float4* o1 = (float4*)(pre1 + (size_t)id * 32);
    float4* o2 = (float4*)(pre2 + (size_t)id * 32);
    #pragma unroll
    for (int q = 0; q < 8; q++) {
        o1[q] = make_float4(s1[4*q], s1[4*q+1], s1[4*q+2], s1[4*q+3]);
        o2[q] = make_float4(s2[4*q], s2[4*q+1], s2[4*q+2], s2[4*q+3]);
    }
    float sp = xv[14] * (wmax[0] - wmin[0]) + wmin[0];
    float dr = xv[15] * (wmax[1] - wmin[1]) + wmin[1];
    ((float2*)wind)[id] = make_float2(sp, dr);
}

// ================= phase B: edge MLP -> g[e][b][16] =================
__global__ __launch_bounds__(256) void edge_mlp(const int* __restrict__ ei,
                                                const float* __restrict__ ea,
                                                const float* __restrict__ pre1,
                                                const float* __restrict__ pre2,
                                                const float* __restrict__ wind,
                                                const float* __restrict__ mm,
                                                const float* __restrict__ W1,
                                                const float* __restrict__ b1,
                                                const float* __restrict__ W2,
                                                const float* __restrict__ b2,
                                                const float* __restrict__ Wn,
                                                float* __restrict__ gbuf,
                                                int b0, int nb) {
    __shared__ float gs[256 * 17];

    const int tid = threadIdx.x;
    const int e = blockIdx.x * 256 + tid;
    const int brel = blockIdx.y;
    const int b = b0 + brel;

    const int src = ei[e];
    const int tgt = ei[EE + e];
    const float2 eav = ((const float2*)ea)[e];
    const float2 wv = ((const float2*)wind)[(size_t)b * NN + src];

    float theta = fabsf(eav.y - wv.y);
    float ew = fmaxf(__fdividef(wv.x * cosf(theta), eav.x), 0.f);
    float ean0 = __fdividef(eav.x - mm[0], mm[2] - mm[0]);
    float ean1 = __fdividef(eav.y - mm[1], mm[3] - mm[1]);

    float h[32];
    const float4* p1 = (const float4*)(pre1 + ((size_t)b * NN + src) * 32);
    const float4* p2 = (const float4*)(pre2 + ((size_t)b * NN + tgt) * 32);
    #pragma unroll
    for (int q = 0; q < 8; q++) {
        float4 a = p1[q];
        float4 c = p2[q];
        h[4*q+0] = a.x + c.x; h[4*q+1] = a.y + c.y;
        h[4*q+2] = a.z + c.z; h[4*q+3] = a.w + c.w;
    }
    #pragma unroll
    for (int j = 0; j < 32; j++) {
        float v = h[j] + ean0 * W1[32 * 32 + j] + ean1 * W1[33 * 32 + j]
                        + ew * W1[34 * 32 + j] + b1[j];
        h[j] = sigmf(v);
    }

    float ef[22];
    #pragma unroll
    for (int k = 0; k < 22; k++) ef[k] = b2[k];
    #pragma unroll
    for (int j = 0; j < 32; j++) {
        float hv = h[j];
        #pragma unroll
        for (int k = 0; k < 22; k++) ef[k] = fmaf(hv, W2[j * 22 + k], ef[k]);
    }
    #pragma unroll
    for (int k = 0; k < 22; k++) ef[k] = sigmf(ef[k]);

    float gg[16];
    #pragma unroll
    for (int i = 0; i < 16; i++) gg[i] = 0.f;
    #pragma unroll
    for (int k = 0; k < 22; k++) {
        float ev = ef[k];
        #pragma unroll
        for (int i = 0; i < 16; i++) gg[i] = fmaf(ev, Wn[k * 16 + i], gg[i]);
    }

    #pragma unroll
    for (int i = 0; i < 16; i++) gs[tid * 17 + i] = gg[i];
    __syncthreads();

    const int c = tid & 15;
    const int base = tid >> 4;
    const size_t ebase = (size_t)blockIdx.x * 256;
    #pragma unroll
    for (int p = 0; p < 16; p++) {
        int s = base + p * 16;
        gbuf[((ebase + s) * (size_t)nb + brel) * 16 + c] = gs[s * 17 + c];
    }
}

// ================= phase C: gather + bn + sigmoid =================
__global__ __launch_bounds__(256) void gather_kernel(const unsigned* __restrict__ offp,
                                                     const unsigned* __restrict__ lst,
                                                     const float* __restrict__ gbuf,
                                                     const float* __restrict__ bn,
                                                     float* __restrict__ out,
                                                     int b0, int nb, int npb, int lgper) {
    int tid = threadIdx.x;
    int n = blockIdx.x * npb + (tid >> lgper);
    int rem = tid & ((1 << lgper) - 1);
    int bi = rem >> 4;
    int c = rem & 15;

    unsigned s0 = offp[n], s1 = offp[n + 1];
    unsigned t0 = offp[NN + 1 + n], t1 = offp[NN + 1 + n + 1];

    float acc = 0.f;
    for (unsigned k = t0; k < t1; k++) {
        int e = (int)lst[EE + k];
        acc += gbuf[((size_t)e * nb + bi) * 16 + c];
    }
    for (unsigned k = s0; k < s1; k++) {
        int e = (int)lst[k];
        acc -= gbuf[((size_t)e * nb + bi) * 16 + c];
    }
    out[((size_t)(b0 + bi) * NN + n) * 16 + c] = sigmf(acc + bn[c]);
}

// ================= fallback (atomic) path, r5-validated =================
__global__ void init_mm(unsigned* mm) {
    int t = threadIdx.x;
    if (t < 2) mm[t] = 0x7F7FFFFFu;
    else if (t < 4) mm[t] = 0u;
}

__global__ __launch_bounds__(256) void minmax_kernel(const float* __restrict__ ea,
                                                     unsigned* __restrict__ mm) {
    int t = blockIdx.x * 256 + threadIdx.x;
    float2 v = ((const float2*)ea)[t];
    float mn0 = v.x, mx0 = v.x, mn1 = v.y, mx1 = v.y;
    #pragma unroll
    for (int off = 32; off >= 1; off >>= 1) {
        mn0 = fminf(mn0, __shfl_xor(mn0, off));
        mx0 = fmaxf(mx0, __shfl_xor(mx0, off));
        mn1 = fminf(mn1, __shfl_xor(mn1, off));
        mx1 = fmaxf(mx1, __shfl_xor(mx1, off));
    }
    if ((threadIdx.x & 63) == 0) {
        atomicMin(&mm[0], __float_as_uint(mn0));
        atomicMin(&mm[1], __float_as_uint(mn1));
        atomicMax(&mm[2], __float_as_uint(mx0));
        atomicMax(&mm[3], __float_as_uint(mx1));
    }
}

__global__ __launch_bounds__(256) void edge_kernel(const int* __restrict__ ei,
                                                   const float* __restrict__ ea,
                                                   const float* __restrict__ pre1,
                                                   const float* __restrict__ pre2,
                                                   const float* __restrict__ wind,
                                                   const float* __restrict__ mm,
                                                   const float* __restrict__ W1,
                                                   const float* __restrict__ b1,
                                                   const float* __restrict__ W2,
                                                   const float* __restrict__ b2,
                                                   const float* __restrict__ Wn,
                                                   float* __restrict__ out) {
    __shared__ float gs[256 * 17];
    __shared__ int nd[512];
    const int tid = threadIdx.x;
    const int e = blockIdx.x * 256 + tid;
    const int b = blockIdx.y;
    const int src = ei[e];
    const int tgt = ei[EE + e];
    const float2 eav = ((const float2*)ea)[e];
    const float2 wv = ((const float2*)wind)[(size_t)b * NN + src];
    float theta = fabsf(eav.y - wv.y);
    float ew = fmaxf(__fdividef(wv.x * cosf(theta), eav.x), 0.f);
    float ean0 = __fdividef(eav.x - mm[0], mm[2] - mm[0]);
    float ean1 = __fdividef(eav.y - mm[1], mm[3] - mm[1]);
    float h[32];
    const float4* p1 = (const float4*)(pre1 + ((size_t)b * NN + src) * 32);
    const float4* p2 = (const float4*)(pre2 + ((size_t)b * NN + tgt) * 32);
    #pragma unroll
    for (int q = 0; q < 8; q++) {
        float4 a = p1[q]; float4 c = p2[q];
        h[4*q+0] = a.x + c.x; h[4*q+1] = a.y + c.y;
        h[4*q+2] = a.z + c.z; h[4*q+3] = a.w + c.w;
    }
    #pragma unroll
    for (int j = 0; j < 32; j++) {
        float v = h[j] + ean0 * W1[32*32+j] + ean1 * W1[33*32+j] + ew * W1[34*32+j] + b1[j];
        h[j] = sigmf(v);
    }
    float ef[22];
    #pragma unroll
    for (int k = 0; k < 22; k++) ef[k] = b2[k];
    #pragma unroll
    for (int j = 0; j < 32; j++) {
        float hv = h[j];
        #pragma unroll
        for (int k = 0; k < 22; k++) ef[k] = fmaf(hv, W2[j*22+k], ef[k]);
    }
    #pragma unroll
    for (int k = 0; k < 22; k++) ef[k] = sigmf(ef[k]);
    float g[16];
    #pragma unroll
    for (int i = 0; i < 16; i++) g[i] = 0.f;
    #pragma unroll
    for (int k = 0; k < 22; k++) {
        float ev = ef[k];
        #pragma unroll
        for (int i = 0; i < 16; i++) g[i] = fmaf(ev, Wn[k*16+i], g[i]);
    }
    nd[tid] = tgt; nd[256 + tid] = src;
    #pragma unroll
    for (int i = 0; i < 16; i++) gs[tid * 17 + i] = g[i];
    __syncthreads();
    const int c = tid & 15;
    const int base = tid >> 4;
    float* aggb = out + (size_t)b * NN * 16;
    for (int p = 0; p < 16; p++) {
        int s = base + p * 16;
        float val = gs[s * 17 + c];
        atomicAdd(&aggb[(size_t)nd[s] * 16 + c], val);
        atomicAdd(&aggb[(size_t)nd[256 + s] * 16 + c], -val);
    }
}

__global__ __launch_bounds__(256) void epilogue(float* __restrict__ out,
                                                const float* __restrict__ bn) {
    int id = blockIdx.x * 256 + threadIdx.x;
    if (id >= BB * NN * 4) return;
    float4 v = ((float4*)out)[id];
    int q = (id & 3) * 4;
    v.x = sigmf(v.x + bn[q + 0]);
    v.y = sigmf(v.y + bn[q + 1]);
    v.z = sigmf(v.z + bn[q + 2]);
    v.w = sigmf(v.w + bn[q + 3]);
    ((float4*)out)[id] = v;
}

extern "C" void kernel_launch(void* const* d_in, const int* in_sizes, int n_in,
                              void* d_out, int out_size, void* d_ws, size_t ws_size,
                              hipStream_t stream) {
    const float* x    = (const float*)d_in[0];
    const int*   ei   = (const int*)d_in[1];
    const float* ea   = (const float*)d_in[2];
    const float* wmin = (const float*)d_in[3];
    const float* wmax = (const float*)d_in[4];
    const float* W1   = (const float*)d_in[5];
    const float* b1   = (const float*)d_in[6];
    const float* W2   = (const float*)d_in[7];
    const float* b2   = (const float*)d_in[8];
    const float* Wn   = (const float*)d_in[9];
    const float* bn   = (const float*)d_in[10];
    float* out = (float*)d_out;

    float* ws       = (float*)d_ws;
    float* mmf      = ws + OFF_MM;
    unsigned* mmu   = (unsigned*)(ws + OFF_MM);
    float* wind     = ws + OFF_WIND;
    float* pre1     = ws + OFF_PRE1;
    float* pre2     = ws + OFF_PRE2;
    unsigned* offp  = (unsigned*)(ws + OFF_OFFP);
    unsigned* tot   = (unsigned*)(ws + OFF_TOT);
    float* mmpart   = ws + OFF_MMP;
    unsigned* cntc  = (unsigned*)(ws + OFF_CNTC);
    unsigned* lst   = (unsigned*)(ws + OFF_LST);
    float* gbuf     = ws + OFF_G;

    int nb = 8;
    while (nb > 1 && ((size_t)OFF_G + (size_t)nb * EE * 16) * 4ull > ws_size) nb >>= 1;
    bool csr_ok = ((size_t)OFF_G + (size_t)nb * EE * 16) * 4ull <= ws_size;

    node_pre<<<(BB * NN + 255) / 256, 256, 0, stream>>>(x, W1, wmin, wmax, pre1, pre2, wind);

    if (csr_ok) {
        count_kernel<<<dim3(NCHUNK, 2), 256, 0, stream>>>(ei, ea, cntc, mmpart);
        tot_kernel<<<dim3((NN + 255) / 256, 2), 256, 0, stream>>>(cntc, tot);
        scan_kernel<<<1, 1024, 0, stream>>>(tot, mmpart, offp, mmf);
        base_kernel<<<dim3((NN + 255) / 256, 2), 256, 0, stream>>>(cntc, offp);
        fill_kernel<<<dim3(NCHUNK, 2), 256, 0, stream>>>(ei, cntc, lst);

        int lgnb = (nb == 8) ? 3 : (nb == 4) ? 2 : (nb == 2) ? 1 : 0;
        int per = 16 * nb;
        int npb = 256 / per;
        int lgper = 4 + lgnb;
        for (int bc = 0; bc < BB; bc += nb) {
            edge_mlp<<<dim3(EE / 256, nb), 256, 0, stream>>>(ei, ea, pre1, pre2, wind,
                                                             mmf, W1, b1, W2, b2, Wn,
                                                             gbuf, bc, nb);
            gather_kernel<<<NN / npb, 256, 0, stream>>>(offp, lst, gbuf, bn, out,
                                                        bc, nb, npb, lgper);
        }
    } else {
        // atomic fallback — r5-validated footprint (nothing past pre2 touched)
        init_mm<<<1, 64, 0, stream>>>(mmu);
        minmax_kernel<<<EE / 256, 256, 0, stream>>>(ea, mmu);
        hipMemsetAsync(d_out, 0, (size_t)out_size * sizeof(float), stream);
        edge_kernel<<<dim3(EE / 256, BB), 256, 0, stream>>>(ei, ea, pre1, pre2, wind,
                                                            mmf, W1, b1, W2, b2, Wn, out);
        epilogue<<<(BB * NN * 4 + 255) / 256, 256, 0, stream>>>(out, bn);
    }
}